// Round 7
// baseline (2072.101 us; speedup 1.0000x reference)
//
#include <hip/hip_runtime.h>

#define TT 2048
#define II 8
#define HH 128
#define OO 96

typedef __attribute__((ext_vector_type(8))) short bf16x8;
typedef __attribute__((ext_vector_type(4))) float f32x4;

__device__ __forceinline__ float fast_rcp(float x) { return __builtin_amdgcn_rcpf(x); }
__device__ __forceinline__ float sigmoid_fast(float x) { return fast_rcp(1.0f + __expf(-x)); }
__device__ __forceinline__ float tanh_fast(float x) {
    return 1.0f - 2.0f * fast_rcp(1.0f + __expf(2.0f * x));
}
__device__ __forceinline__ unsigned short f2bf(float f) {
    unsigned int u = __builtin_bit_cast(unsigned int, f);
    u += 0x7fffu + ((u >> 16) & 1u);   // RNE
    return (unsigned short)(u >> 16);
}
__device__ __forceinline__ float bf2f(unsigned short h) {
    unsigned int u = ((unsigned int)h) << 16;
    return __builtin_bit_cast(float, u);
}
// x(t) -> (hi, lo) bf16x8 split
__device__ __forceinline__ void cvt_x(float4 a, float4 b, bf16x8& hi, bf16x8& lo) {
    float v[8] = {a.x, a.y, a.z, a.w, b.x, b.y, b.z, b.w};
#pragma unroll
    for (int i = 0; i < 8; ++i) {
        unsigned short s = f2bf(v[i]);
        hi[i] = (short)s;
        lo[i] = (short)f2bf(v[i] - bf2f(s));
    }
}

// Block = 4 waves (256 thr) = ONE batch row; grid 512 -> 2 independent blocks/CU
// (2 waves/SIMD from different blocks; private barriers interleave chains).
// Wave wv: j-tiles {32wv..+15, 32wv+16..+31}, MFMA 16x16x32, K=160:
//   k = [h(128) | x(8) | bias-1.0 slot @136 | 0pad]; A rows: plane = m&1 (even=h_hi, odd=h_lo).
// gh+gx+bias = C[0]+C[1] (bf16 split compensation). n-gate: x,b_ih_n kept outside r*(.) via cX.
// LDS h: [buf][plane][128 bf16] = 2 x 512B.
__global__ __launch_bounds__(256, 2) void gru_kernel(
    const float* __restrict__ x,     // [B, T, I]
    const float* __restrict__ w_ih,  // [3H, I]
    const float* __restrict__ w_hh,  // [3H, H]
    const float* __restrict__ b_ih,  // [3H]
    const float* __restrict__ b_hh,  // [3H]
    const float* __restrict__ fc_w,  // [O, H]
    const float* __restrict__ fc_b,  // [O]
    float* __restrict__ out)         // [B, O]
{
    __shared__ __align__(16) char hb[2 * 512];
    __shared__ __align__(16) float hfin[HH];

    const int tid = threadIdx.x;
    const int wv  = tid >> 6;
    const int ln  = tid & 63;
    const int col = ln & 15;       // m row (and C col = j)
    const int g4  = ln >> 4;       // k-subblock
    const int p   = col & 1;       // A plane: even rows hi, odd rows lo
    const int b   = blockIdx.x;
    const int j0  = 32 * wv + col;
    const int j1  = j0 + 16;

    // ---- weight-stationary B fragments (bf16) ----
    auto ld_hh = [&](int grow, int c) {
        const float* rp = w_hh + grow * HH + 32 * c + g4 * 8;
        float4 u = *(const float4*)(rp);
        float4 v = *(const float4*)(rp + 4);
        bf16x8 f;
        f[0] = (short)f2bf(u.x); f[1] = (short)f2bf(u.y);
        f[2] = (short)f2bf(u.z); f[3] = (short)f2bf(u.w);
        f[4] = (short)f2bf(v.x); f[5] = (short)f2bf(v.y);
        f[6] = (short)f2bf(v.z); f[7] = (short)f2bf(v.w);
        return f;
    };
    // tail (k=128..159): g4==0 -> W_ih row (x area), g4==1 i==0 (k=136) -> bias
    auto ld_tail = [&](const float* xw, float bias) {
        bf16x8 f = {0, 0, 0, 0, 0, 0, 0, 0};
        if (g4 == 0 && xw) {
            float4 u = *(const float4*)(xw);
            float4 v = *(const float4*)(xw + 4);
            f[0] = (short)f2bf(u.x); f[1] = (short)f2bf(u.y);
            f[2] = (short)f2bf(u.z); f[3] = (short)f2bf(u.w);
            f[4] = (short)f2bf(v.x); f[5] = (short)f2bf(v.y);
            f[6] = (short)f2bf(v.z); f[7] = (short)f2bf(v.w);
        } else if (g4 == 1) {
            f[0] = (short)f2bf(bias);
        }
        return f;
    };

    bf16x8 bR0[5], bZ0[5], bN0[5], bR1[5], bZ1[5], bN1[5], bX0, bX1;
#pragma unroll
    for (int c = 0; c < 4; ++c) {
        bR0[c] = ld_hh(j0, c);          bR1[c] = ld_hh(j1, c);
        bZ0[c] = ld_hh(HH + j0, c);     bZ1[c] = ld_hh(HH + j1, c);
        bN0[c] = ld_hh(2 * HH + j0, c); bN1[c] = ld_hh(2 * HH + j1, c);
    }
    bR0[4] = ld_tail(w_ih + (size_t)j0 * II,            b_ih[j0] + b_hh[j0]);
    bR1[4] = ld_tail(w_ih + (size_t)j1 * II,            b_ih[j1] + b_hh[j1]);
    bZ0[4] = ld_tail(w_ih + (size_t)(HH + j0) * II,     b_ih[HH + j0] + b_hh[HH + j0]);
    bZ1[4] = ld_tail(w_ih + (size_t)(HH + j1) * II,     b_ih[HH + j1] + b_hh[HH + j1]);
    bN0[4] = ld_tail(nullptr,                           b_hh[2 * HH + j0]);  // inside r*(.)
    bN1[4] = ld_tail(nullptr,                           b_hh[2 * HH + j1]);
    bX0    = ld_tail(w_ih + (size_t)(2 * HH + j0) * II, b_ih[2 * HH + j0]);  // outside
    bX1    = ld_tail(w_ih + (size_t)(2 * HH + j1) * II, b_ih[2 * HH + j1]);

    // ---- zero both h buffers (h(0)=0) ----
    if (tid < 256) ((int*)hb)[tid] = 0;
    __syncthreads();

    // ---- x prefetch/convert (uniform per block) ----
    const float* xr = x + (size_t)b * TT * II;
    bf16x8 xh0, xl0, xh1, xl1;
    cvt_x(*(const float4*)(xr), *(const float4*)(xr + 4), xh0, xl0);             // x(0)
    cvt_x(*(const float4*)(xr + II), *(const float4*)(xr + II + 4), xh1, xl1);   // x(1)

    const char* ar = hb + p * 256 + g4 * 16;
    char* hw = hb;
    float h0 = 0.f, h1 = 0.f;
    const f32x4 zf = {0.f, 0.f, 0.f, 0.f};
    bf16x8 zero8 = {0, 0, 0, 0, 0, 0, 0, 0};
    bf16x8 one8  = zero8; one8[0] = (short)0x3F80;

#define STEP(BUF, XH, XL)                                                        \
    {                                                                            \
        const char* ab = ar + (BUF) * 512;                                       \
        bf16x8 a0 = *(const bf16x8*)(ab);                                        \
        bf16x8 a1 = *(const bf16x8*)(ab + 64);                                   \
        bf16x8 a2 = *(const bf16x8*)(ab + 128);                                  \
        bf16x8 a3 = *(const bf16x8*)(ab + 192);                                  \
        bf16x8 a4 = (g4 == 0) ? (p ? (XL) : (XH))                                \
                  : ((g4 == 1) ? (p ? zero8 : one8) : zero8);                    \
        f32x4 cR0 = __builtin_amdgcn_mfma_f32_16x16x32_bf16(a4, bR0[4], zf, 0, 0, 0); \
        f32x4 cZ0 = __builtin_amdgcn_mfma_f32_16x16x32_bf16(a4, bZ0[4], zf, 0, 0, 0); \
        f32x4 cN0 = __builtin_amdgcn_mfma_f32_16x16x32_bf16(a4, bN0[4], zf, 0, 0, 0); \
        f32x4 cX0 = __builtin_amdgcn_mfma_f32_16x16x32_bf16(a4, bX0,    zf, 0, 0, 0); \
        f32x4 cR1 = __builtin_amdgcn_mfma_f32_16x16x32_bf16(a4, bR1[4], zf, 0, 0, 0); \
        f32x4 cZ1 = __builtin_amdgcn_mfma_f32_16x16x32_bf16(a4, bZ1[4], zf, 0, 0, 0); \
        f32x4 cN1 = __builtin_amdgcn_mfma_f32_16x16x32_bf16(a4, bN1[4], zf, 0, 0, 0); \
        f32x4 cX1 = __builtin_amdgcn_mfma_f32_16x16x32_bf16(a4, bX1,    zf, 0, 0, 0); \
        _Pragma("unroll")                                                        \
        for (int c = 0; c < 4; ++c) {                                            \
            bf16x8 ac = (c == 0) ? a0 : (c == 1) ? a1 : (c == 2) ? a2 : a3;      \
            cR0 = __builtin_amdgcn_mfma_f32_16x16x32_bf16(ac, bR0[c], cR0, 0, 0, 0); \
            cZ0 = __builtin_amdgcn_mfma_f32_16x16x32_bf16(ac, bZ0[c], cZ0, 0, 0, 0); \
            cN0 = __builtin_amdgcn_mfma_f32_16x16x32_bf16(ac, bN0[c], cN0, 0, 0, 0); \
            cR1 = __builtin_amdgcn_mfma_f32_16x16x32_bf16(ac, bR1[c], cR1, 0, 0, 0); \
            cZ1 = __builtin_amdgcn_mfma_f32_16x16x32_bf16(ac, bZ1[c], cZ1, 0, 0, 0); \
            cN1 = __builtin_amdgcn_mfma_f32_16x16x32_bf16(ac, bN1[c], cN1, 0, 0, 0); \
        }                                                                        \
        float gr0 = cR0[0] + cR0[1], gz0 = cZ0[0] + cZ0[1];                      \
        float gn0 = cN0[0] + cN0[1], gx0 = cX0[0] + cX0[1];                      \
        float gr1 = cR1[0] + cR1[1], gz1 = cZ1[0] + cZ1[1];                      \
        float gn1 = cN1[0] + cN1[1], gx1 = cX1[0] + cX1[1];                      \
        float r0 = sigmoid_fast(gr0), z0 = sigmoid_fast(gz0);                    \
        float n0 = tanh_fast(fmaf(r0, gn0, gx0));                                \
        h0 = fmaf(z0, h0 - n0, n0);                                              \
        float r1 = sigmoid_fast(gr1), z1 = sigmoid_fast(gz1);                    \
        float n1 = tanh_fast(fmaf(r1, gn1, gx1));                                \
        h1 = fmaf(z1, h1 - n1, n1);                                              \
        if (g4 == 0) {                                                           \
            char* nb = hw + (1 - (BUF)) * 512;                                   \
            unsigned short s0 = f2bf(h0), s1 = f2bf(h1);                         \
            *(unsigned short*)(nb + j0 * 2)       = s0;                          \
            *(unsigned short*)(nb + 256 + j0 * 2) = f2bf(h0 - bf2f(s0));         \
            *(unsigned short*)(nb + j1 * 2)       = s1;                          \
            *(unsigned short*)(nb + 256 + j1 * 2) = f2bf(h1 - bf2f(s1));         \
        }                                                                        \
        __syncthreads();                                                         \
    }

    for (int it = 0; it < TT / 2; ++it) {
        // prefetch + convert x(2it+2), x(2it+3) — off the critical path
        int t2 = 2 * it + 2; if (t2 >= TT) t2 = TT - 1;
        int t3 = 2 * it + 3; if (t3 >= TT) t3 = TT - 1;
        bf16x8 nh0, nl0, nh1, nl1;
        cvt_x(*(const float4*)(xr + t2 * II), *(const float4*)(xr + t2 * II + 4), nh0, nl0);
        cvt_x(*(const float4*)(xr + t3 * II), *(const float4*)(xr + t3 * II + 4), nh1, nl1);

        STEP(0, xh0, xl0)   // t even: read buf0, write buf1
        STEP(1, xh1, xl1)   // t odd:  read buf1, write buf0

        xh0 = nh0; xl0 = nl0; xh1 = nh1; xl1 = nl1;
    }
#undef STEP

    // ---- epilogue FC (h in regs, fp32) ----
    if (g4 == 0) { hfin[j0] = h0; hfin[j1] = h1; }
    __syncthreads();

    if (tid < OO) {
        const int o = tid;
        const float4* hf = (const float4*)(&hfin[0]);
        const float4* wp = (const float4*)(fc_w + o * HH);
        float acc = fc_b[o];
#pragma unroll 8
        for (int v = 0; v < HH / 4; ++v) {
            float4 w4 = wp[v];
            float4 h4 = hf[v];
            acc = fmaf(w4.x, h4.x, acc); acc = fmaf(w4.y, h4.y, acc);
            acc = fmaf(w4.z, h4.z, acc); acc = fmaf(w4.w, h4.w, acc);
        }
        out[(size_t)b * OO + o] = acc;
    }
}

extern "C" void kernel_launch(void* const* d_in, const int* in_sizes, int n_in,
                              void* d_out, int out_size, void* d_ws, size_t ws_size,
                              hipStream_t stream) {
    const float* x    = (const float*)d_in[0];
    const float* w_ih = (const float*)d_in[1];
    const float* w_hh = (const float*)d_in[2];
    const float* b_ih = (const float*)d_in[3];
    const float* b_hh = (const float*)d_in[4];
    const float* fc_w = (const float*)d_in[5];
    const float* fc_b = (const float*)d_in[6];
    float* out = (float*)d_out;

    gru_kernel<<<512, 256, 0, stream>>>(x, w_ih, w_hh, b_ih, b_hh, fc_w, fc_b, out);
}

// Round 8
// 1386.906 us; speedup vs baseline: 1.4940x; 1.4940x over previous
//
#include <hip/hip_runtime.h>

#define TT 2048
#define II 8
#define HH 128
#define OO 96
#define PL 320            // A-plane stride (bytes): k=0..159 bf16; 2-way bank alias only (free)
#define BUFB (4 * PL)     // 1280 B per buffer

typedef __attribute__((ext_vector_type(8))) short bf16x8;
typedef __attribute__((ext_vector_type(4))) float f32x4;

__device__ __forceinline__ float fast_rcp(float x) { return __builtin_amdgcn_rcpf(x); }
__device__ __forceinline__ float sigmoid_fast(float x) { return fast_rcp(1.0f + __expf(-x)); }
__device__ __forceinline__ float tanh_fast(float x) {
    return 1.0f - 2.0f * fast_rcp(1.0f + __expf(2.0f * x));
}
__device__ __forceinline__ unsigned short f2bf(float f) {
    unsigned int u = __builtin_bit_cast(unsigned int, f);
    u += 0x7fffu + ((u >> 16) & 1u);   // RNE
    return (unsigned short)(u >> 16);
}
__device__ __forceinline__ float bf2f(unsigned short h) {
    unsigned int u = ((unsigned int)h) << 16;
    return __builtin_bit_cast(float, u);
}

// Block = 4 waves (256 thr), 2 batch rows, full T scan; grid 256 (1 block/CU).
// Wave wv owns j-tiles {j_a=32wv+col, j_b=j_a+16}; A-frags (5 ds_read_b128) are
// SHARED across both tiles -> LDS burst 20 reads/CU-step (R3 had 40).
// MFMA 16x16x32, K=160: k=[h(128) | x(8) | 1.0-bias@136 | 0pad].
// A planes (m&3): {0:b0hi, 1:b1hi, 2:b0lo, 3:b1lo}; gh(b0)=C[0]+C[2], gh(b1)=C[1]+C[3].
// Biases folded into MFMA via k=136 slot (1.0 in hi planes only).
__global__ __launch_bounds__(256, 1) void gru_kernel(
    const float* __restrict__ x,     // [B, T, I]
    const float* __restrict__ w_ih,  // [3H, I]
    const float* __restrict__ w_hh,  // [3H, H]
    const float* __restrict__ b_ih,  // [3H]
    const float* __restrict__ b_hh,  // [3H]
    const float* __restrict__ fc_w,  // [O, H]
    const float* __restrict__ fc_b,  // [O]
    float* __restrict__ out)         // [B, O]
{
    __shared__ __align__(16) char hbuf[2 * BUFB];
    __shared__ __align__(16) float hfin[2][HH];

    const int tid = threadIdx.x;
    const int wv  = tid >> 6;      // 0..3
    const int ln  = tid & 63;
    const int col = ln & 15;       // A-row m / C col
    const int g4  = ln >> 4;       // k-subblock
    const int p   = col & 3;       // A plane
    const int b0  = blockIdx.x * 2;
    const int j_a = 32 * wv + col;
    const int j_b = j_a + 16;

    // ---- weight-stationary B fragments (bf16): B[k=g4*8+i+32c][n=j] ----
    auto ld_hh = [&](int grow, int c) {
        const float* rp = w_hh + grow * HH + 32 * c + g4 * 8;
        float4 u = *(const float4*)(rp);
        float4 v = *(const float4*)(rp + 4);
        bf16x8 f;
        f[0] = (short)f2bf(u.x); f[1] = (short)f2bf(u.y);
        f[2] = (short)f2bf(u.z); f[3] = (short)f2bf(u.w);
        f[4] = (short)f2bf(v.x); f[5] = (short)f2bf(v.y);
        f[6] = (short)f2bf(v.z); f[7] = (short)f2bf(v.w);
        return f;
    };
    // tail c=4 (k=128..159): g4==0 -> W_ih (x area k=128..135); g4==1 -> bias at k=136
    auto ld_tail = [&](const float* xw, float bias) {
        bf16x8 f = {0, 0, 0, 0, 0, 0, 0, 0};
        if (g4 == 0 && xw) {
            float4 u = *(const float4*)(xw);
            float4 v = *(const float4*)(xw + 4);
            f[0] = (short)f2bf(u.x); f[1] = (short)f2bf(u.y);
            f[2] = (short)f2bf(u.z); f[3] = (short)f2bf(u.w);
            f[4] = (short)f2bf(v.x); f[5] = (short)f2bf(v.y);
            f[6] = (short)f2bf(v.z); f[7] = (short)f2bf(v.w);
        } else if (g4 == 1) {
            f[0] = (short)f2bf(bias);
        }
        return f;
    };

    bf16x8 bRa[5], bZa[5], bNa[5], bXa, bRb[5], bZb[5], bNb[5], bXb;
#pragma unroll
    for (int c = 0; c < 4; ++c) {
        bRa[c] = ld_hh(j_a, c);          bRb[c] = ld_hh(j_b, c);
        bZa[c] = ld_hh(HH + j_a, c);     bZb[c] = ld_hh(HH + j_b, c);
        bNa[c] = ld_hh(2 * HH + j_a, c); bNb[c] = ld_hh(2 * HH + j_b, c);
    }
    bRa[4] = ld_tail(w_ih + (size_t)j_a * II,            b_ih[j_a] + b_hh[j_a]);
    bRb[4] = ld_tail(w_ih + (size_t)j_b * II,            b_ih[j_b] + b_hh[j_b]);
    bZa[4] = ld_tail(w_ih + (size_t)(HH + j_a) * II,     b_ih[HH + j_a] + b_hh[HH + j_a]);
    bZb[4] = ld_tail(w_ih + (size_t)(HH + j_b) * II,     b_ih[HH + j_b] + b_hh[HH + j_b]);
    bNa[4] = ld_tail(nullptr,                            b_hh[2 * HH + j_a]);  // inside r*(.)
    bNb[4] = ld_tail(nullptr,                            b_hh[2 * HH + j_b]);
    bXa    = ld_tail(w_ih + (size_t)(2 * HH + j_a) * II, b_ih[2 * HH + j_a]);  // outside
    bXb    = ld_tail(w_ih + (size_t)(2 * HH + j_b) * II, b_ih[2 * HH + j_b]);

    // ---- zero both LDS buffers, then set bias slots ----
    for (int i = tid; i < (2 * BUFB) / 4; i += 256) ((int*)hbuf)[i] = 0;
    __syncthreads();
    if (tid < 4) {   // bias 1.0 at k=136 (byte 272) in hi planes (0,1) of both buffers
        char* pb = hbuf + (tid >> 1) * BUFB + (tid & 1) * PL + 272;
        *(unsigned short*)pb = 0x3F80;
    }
    // x staging t=0: wave 3 lanes 0..15 (b = ln>>3, i = ln&7)
    const float* xr = x + (size_t)(b0 + (ln >> 3)) * TT * II + (ln & 7);
    float xc1 = 0.f, xc2 = 0.f;
    if (wv == 3 && ln < 16) {
        float x0 = xr[0];
        xc1 = xr[II];
        xc2 = xr[2 * II];
        unsigned short xh = f2bf(x0);
        char* xw = hbuf + (ln >> 3) * PL + (128 + (ln & 7)) * 2;  // buf0, hi plane = b
        *(unsigned short*)(xw)          = xh;
        *(unsigned short*)(xw + 2 * PL) = f2bf(x0 - bf2f(xh));    // lo plane = b+2
    }
    __syncthreads();

    const char* ar = hbuf + p * PL + g4 * 16;
    float h0a = 0.f, h1a = 0.f, h0b = 0.f, h1b = 0.f;
    const f32x4 zf = {0.f, 0.f, 0.f, 0.f};

#define STEP(BUF, XVAL)                                                          \
    {                                                                            \
        const char* ab = ar + (BUF) * BUFB;                                      \
        bf16x8 a0 = *(const bf16x8*)(ab);                                        \
        bf16x8 a1 = *(const bf16x8*)(ab + 64);                                   \
        bf16x8 a2 = *(const bf16x8*)(ab + 128);                                  \
        bf16x8 a3 = *(const bf16x8*)(ab + 192);                                  \
        bf16x8 a4 = *(const bf16x8*)(ab + 256);                                  \
        /* 8 independent chains (4 per tile), depth <= 5 */                      \
        f32x4 cRa = __builtin_amdgcn_mfma_f32_16x16x32_bf16(a4, bRa[4], zf, 0, 0, 0); \
        f32x4 cZa = __builtin_amdgcn_mfma_f32_16x16x32_bf16(a4, bZa[4], zf, 0, 0, 0); \
        f32x4 cNa = __builtin_amdgcn_mfma_f32_16x16x32_bf16(a4, bNa[4], zf, 0, 0, 0); \
        f32x4 cXa = __builtin_amdgcn_mfma_f32_16x16x32_bf16(a4, bXa,    zf, 0, 0, 0); \
        f32x4 cRb = __builtin_amdgcn_mfma_f32_16x16x32_bf16(a4, bRb[4], zf, 0, 0, 0); \
        f32x4 cZb = __builtin_amdgcn_mfma_f32_16x16x32_bf16(a4, bZb[4], zf, 0, 0, 0); \
        f32x4 cNb = __builtin_amdgcn_mfma_f32_16x16x32_bf16(a4, bNb[4], zf, 0, 0, 0); \
        f32x4 cXb = __builtin_amdgcn_mfma_f32_16x16x32_bf16(a4, bXb,    zf, 0, 0, 0); \
        _Pragma("unroll")                                                        \
        for (int c = 0; c < 4; ++c) {                                            \
            bf16x8 ac = (c == 0) ? a0 : (c == 1) ? a1 : (c == 2) ? a2 : a3;      \
            cRa = __builtin_amdgcn_mfma_f32_16x16x32_bf16(ac, bRa[c], cRa, 0, 0, 0); \
            cZa = __builtin_amdgcn_mfma_f32_16x16x32_bf16(ac, bZa[c], cZa, 0, 0, 0); \
            cNa = __builtin_amdgcn_mfma_f32_16x16x32_bf16(ac, bNa[c], cNa, 0, 0, 0); \
            cRb = __builtin_amdgcn_mfma_f32_16x16x32_bf16(ac, bRb[c], cRb, 0, 0, 0); \
            cZb = __builtin_amdgcn_mfma_f32_16x16x32_bf16(ac, bZb[c], cZb, 0, 0, 0); \
            cNb = __builtin_amdgcn_mfma_f32_16x16x32_bf16(ac, bNb[c], cNb, 0, 0, 0); \
        }                                                                        \
        /* planes: C[0]=b0hi, C[1]=b1hi, C[2]=b0lo, C[3]=b1lo */                 \
        float gra0 = cRa[0] + cRa[2], gra1 = cRa[1] + cRa[3];                    \
        float gza0 = cZa[0] + cZa[2], gza1 = cZa[1] + cZa[3];                    \
        float gna0 = cNa[0] + cNa[2], gna1 = cNa[1] + cNa[3];                    \
        float gxa0 = cXa[0] + cXa[2], gxa1 = cXa[1] + cXa[3];                    \
        float grb0 = cRb[0] + cRb[2], grb1 = cRb[1] + cRb[3];                    \
        float gzb0 = cZb[0] + cZb[2], gzb1 = cZb[1] + cZb[3];                    \
        float gnb0 = cNb[0] + cNb[2], gnb1 = cNb[1] + cNb[3];                    \
        float gxb0 = cXb[0] + cXb[2], gxb1 = cXb[1] + cXb[3];                    \
        float r0a = sigmoid_fast(gra0), z0a = sigmoid_fast(gza0);                \
        float n0a = tanh_fast(fmaf(r0a, gna0, gxa0));                            \
        h0a = fmaf(z0a, h0a - n0a, n0a);                                         \
        float r1a = sigmoid_fast(gra1), z1a = sigmoid_fast(gza1);                \
        float n1a = tanh_fast(fmaf(r1a, gna1, gxa1));                            \
        h1a = fmaf(z1a, h1a - n1a, n1a);                                         \
        float r0b = sigmoid_fast(grb0), z0b = sigmoid_fast(gzb0);                \
        float n0b = tanh_fast(fmaf(r0b, gnb0, gxb0));                            \
        h0b = fmaf(z0b, h0b - n0b, n0b);                                         \
        float r1b = sigmoid_fast(grb1), z1b = sigmoid_fast(gzb1);                \
        float n1b = tanh_fast(fmaf(r1b, gnb1, gxb1));                            \
        h1b = fmaf(z1b, h1b - n1b, n1b);                                         \
        /* distributed writeback: lane writes ONE (row,j) hi+lo pair by g4 */    \
        char* nb = hbuf + (1 - (BUF)) * BUFB;                                    \
        float hv = (g4 == 0) ? h0a : (g4 == 1) ? h1a : (g4 == 2) ? h0b : h1b;    \
        const int jw = (g4 < 2) ? j_a : j_b;                                     \
        unsigned short sv = f2bf(hv);                                            \
        char* wp_ = nb + (g4 & 1) * PL + jw * 2;                                 \
        *(unsigned short*)(wp_)          = sv;                                   \
        *(unsigned short*)(wp_ + 2 * PL) = f2bf(hv - bf2f(sv));                  \
        if (wv == 3 && ln < 16) {                                                \
            unsigned short xh = f2bf(XVAL);                                      \
            char* xw = nb + (ln >> 3) * PL + (128 + (ln & 7)) * 2;               \
            *(unsigned short*)(xw)          = xh;                                \
            *(unsigned short*)(xw + 2 * PL) = f2bf((XVAL) - bf2f(xh));           \
        }                                                                        \
        __syncthreads();                                                         \
    }

    for (int it = 0; it < TT / 2; ++it) {
        float xn1 = 0.f, xn2 = 0.f;
        if (wv == 3 && ln < 16) {                    // prefetch x(t+3), x(t+4)
            int t3 = 2 * it + 3; if (t3 >= TT) t3 = TT - 1;
            int t4 = 2 * it + 4; if (t4 >= TT) t4 = TT - 1;
            xn1 = xr[t3 * II];
            xn2 = xr[t4 * II];
        }
        STEP(0, xc1)    // even t: read buf0, write buf1
        STEP(1, xc2)    // odd  t: read buf1, write buf0
        xc1 = xn1; xc2 = xn2;
    }
#undef STEP

    // ---- epilogue FC ----
    if (g4 == 0)      hfin[0][j_a] = h0a;
    else if (g4 == 1) hfin[1][j_a] = h1a;
    else if (g4 == 2) hfin[0][j_b] = h0b;
    else              hfin[1][j_b] = h1b;
    __syncthreads();

    if (tid < 2 * OO) {
        const int bb2 = (tid >= OO) ? 1 : 0;
        const int o   = tid - OO * bb2;
        const float4* hf = (const float4*)(&hfin[bb2][0]);
        const float4* wp = (const float4*)(fc_w + o * HH);
        float acc = fc_b[o];
#pragma unroll 8
        for (int v = 0; v < HH / 4; ++v) {
            float4 w4 = wp[v];
            float4 h4 = hf[v];
            acc = fmaf(w4.x, h4.x, acc); acc = fmaf(w4.y, h4.y, acc);
            acc = fmaf(w4.z, h4.z, acc); acc = fmaf(w4.w, h4.w, acc);
        }
        out[(size_t)(b0 + bb2) * OO + o] = acc;
    }
}

extern "C" void kernel_launch(void* const* d_in, const int* in_sizes, int n_in,
                              void* d_out, int out_size, void* d_ws, size_t ws_size,
                              hipStream_t stream) {
    const float* x    = (const float*)d_in[0];
    const float* w_ih = (const float*)d_in[1];
    const float* w_hh = (const float*)d_in[2];
    const float* b_ih = (const float*)d_in[3];
    const float* b_hh = (const float*)d_in[4];
    const float* fc_w = (const float*)d_in[5];
    const float* fc_b = (const float*)d_in[6];
    float* out = (float*)d_out;

    gru_kernel<<<256, 256, 0, stream>>>(x, w_ih, w_hh, b_ih, b_hh, fc_w, fc_b, out);
}